// Round 12
// baseline (165.364 us; speedup 1.0000x reference)
//
#include <hip/hip_runtime.h>

#define N_ 4096
#define C_ 256
#define H_ 16
#define D_ 64
#define HD_ 1024

typedef __attribute__((ext_vector_type(8))) _Float16 f16x8;
typedef __attribute__((ext_vector_type(4))) _Float16 f16x4;
typedef __attribute__((ext_vector_type(4))) float f32x4;

__device__ __forceinline__ void gload16(const void* g, void* l) {
    __builtin_amdgcn_global_load_lds(
        (const __attribute__((address_space(1))) unsigned int*)g,
        (__attribute__((address_space(3))) unsigned int*)l, 16, 0, 0);
}

// ---------------------------------------------------------------------------
// Kernel 0: convert fp32 inputs -> fp16 (X, Wq..Wg, Wo; W transposed
// K-contiguous) + bias band pack into bpF[t][256][64] fp32. (R17, unchanged)
// ---------------------------------------------------------------------------
__global__ __launch_bounds__(256) void convert_kernel(
    const float* __restrict__ q_x, const float* __restrict__ kv_x,
    const float* __restrict__ bias,
    const float* __restrict__ Wq, const float* __restrict__ Wk,
    const float* __restrict__ Wv, const float* __restrict__ Wg,
    const float* __restrict__ Wo,
    _Float16* __restrict__ Xf, _Float16* __restrict__ WTf,
    _Float16* __restrict__ WoTf, float* __restrict__ bpF)
{
    __shared__ float ts[64][65];
    const int b = blockIdx.x;
    const int tid = threadIdx.x;

    if (b < 512) {
        const int seg = b >> 8;
        const float* src = seg ? kv_x : q_x;
        _Float16* df = Xf + (size_t)seg * 1048576;
        const int base = (b & 255) * 4096 + tid * 16;
#pragma unroll
        for (int q = 0; q < 4; ++q) {
            float4 v = *(const float4*)&src[base + q * 4];
            f16x4 fv;
            fv[0] = (_Float16)v.x; fv[1] = (_Float16)v.y;
            fv[2] = (_Float16)v.z; fv[3] = (_Float16)v.w;
            *(f16x4*)&df[base + q * 4] = fv;
        }
        return;
    }

    if (b >= 832) {
        const int t = b - 832;
        const int kb = t * 64 - 96;
        float* bpT = bpF + (size_t)t * 16384;
#pragma unroll
        for (int cc = 0; cc < 4; ++cc) {
            if (cc) __syncthreads();
            {
                const int q = tid >> 2;
                const float* brow = bias + (size_t)(t * 64 + q) * 4096;
#pragma unroll
                for (int u = 0; u < 4; ++u) {
                    const int lc = (tid & 3) * 16 + u * 4;
                    const int kg = kb + cc * 64 + lc;
                    float4 v = make_float4(0.f, 0.f, 0.f, 0.f);
                    if ((unsigned)kg < 4093u) v = *(const float4*)&brow[kg];
                    ts[q][lc + 0] = v.x; ts[q][lc + 1] = v.y;
                    ts[q][lc + 2] = v.z; ts[q][lc + 3] = v.w;
                }
            }
            __syncthreads();
            {
                const int s = tid >> 2;              // local slot 0..63
                const int qseg = (tid & 3) * 16;
                float* drow = bpT + (size_t)(cc * 64 + s) * 64 + qseg;
#pragma unroll
                for (int u = 0; u < 4; ++u) {
                    float4 v;
                    v.x = ts[qseg + u * 4 + 0][s];
                    v.y = ts[qseg + u * 4 + 1][s];
                    v.z = ts[qseg + u * 4 + 2][s];
                    v.w = ts[qseg + u * 4 + 3][s];
                    *(float4*)&drow[u * 4] = v;
                }
            }
        }
        return;
    }

    const float* src;
    _Float16* df;
    int srcC, dstC, r0, c0;
    if (b < 768) {
        const int widx = (b - 512) >> 6;
        const int tile = (b - 512) & 63;
        src = (widx == 0) ? Wq : (widx == 1) ? Wk : (widx == 2) ? Wv : Wg;
        df = WTf + (size_t)widx * 262144;
        srcC = 1024; dstC = 256;
        r0 = (tile >> 4) * 64;
        c0 = (tile & 15) * 64;
    } else {
        const int tile = b - 768;
        src = Wo; df = WoTf;
        srcC = 256; dstC = 1024;
        r0 = (tile >> 2) * 64;
        c0 = (tile & 3) * 64;
    }
    {
        const int r = tid >> 2;
        const int cch = (tid & 3) * 16;
#pragma unroll
        for (int q = 0; q < 4; ++q) {
            float4 v = *(const float4*)&src[(size_t)(r0 + r) * srcC + c0 + cch + q * 4];
            ts[r][cch + q * 4 + 0] = v.x;
            ts[r][cch + q * 4 + 1] = v.y;
            ts[r][cch + q * 4 + 2] = v.z;
            ts[r][cch + q * 4 + 3] = v.w;
        }
    }
    __syncthreads();
    {
        const int c = tid >> 2;
        const int rch = (tid & 3) * 16;
#pragma unroll
        for (int q = 0; q < 4; ++q) {
            f16x4 fv;
#pragma unroll
            for (int j = 0; j < 4; ++j)
                fv[j] = (_Float16)ts[rch + q * 4 + j][c];
            *(f16x4*)&df[(size_t)(c0 + c) * dstC + r0 + rch + q * 4] = fv;
        }
    }
}

// ---------------------------------------------------------------------------
// Kernel 1: projections via fp16 MFMA. (R16 geometry, the measured best:
// 64x128 tile, 2048 blocks, simple stage->drain loop, 24 KB LDS. R18's
// counted-vmcnt and R20's 64x64 probes both failed to beat it.)
// ---------------------------------------------------------------------------
__global__ __launch_bounds__(256) void proj_mfma(
    const _Float16* __restrict__ Xf, const _Float16* __restrict__ WTf,
    _Float16* __restrict__ qh, _Float16* __restrict__ kh,
    _Float16* __restrict__ vt, _Float16* __restrict__ gh)
{
    __shared__ __align__(16) char psmem[24576];
    _Float16* As = (_Float16*)psmem;             // [64][64] swz, 8 KB
    _Float16* Bs = (_Float16*)(psmem + 8192);    // [128][64] swz, 16 KB

    const int lb  = blockIdx.x;                  // 0..2047
    const int xcd = lb & 7;
    const int gr  = (lb >> 6) * 8 + xcd;         // 0..255 -> (g, row-tile)
    const int g   = gr >> 6;
    const int m0  = (gr & 63) * 64;
    const int c0  = ((lb >> 3) & 7) * 128;

    const _Float16* A = Xf + ((g == 1 || g == 2) ? 1048576 : 0);
    const _Float16* B = WTf + (size_t)g * 262144;

    const int tid  = threadIdx.x;
    const int wv   = tid >> 6;                   // wave 0..3 = 16-row strip
    const int lane = tid & 63;
    const int frow = lane & 15;
    const int grp  = lane >> 4;

    f32x4 acc[8];
#pragma unroll
    for (int j = 0; j < 8; ++j) acc[j] = (f32x4){0.f, 0.f, 0.f, 0.f};

    const int srow = tid >> 3;
    const int sch  = tid & 7;

    for (int kt = 0; kt < 256; kt += 64) {
        __syncthreads();
#pragma unroll
        for (int p = 0; p < 2; ++p) {            // A: 64 rows x 64 k = 8 KB
            const int row = p * 32 + srow;
            const int koff = kt + ((sch ^ (row & 7)) << 3);
            gload16(A + (size_t)(m0 + row) * 256 + koff, (char*)As + p * 4096 + tid * 16);
        }
#pragma unroll
        for (int p = 0; p < 4; ++p) {            // B: 128 rows x 64 k = 16 KB
            const int row = p * 32 + srow;
            const int koff = kt + ((sch ^ (row & 7)) << 3);
            gload16(B + (size_t)(c0 + row) * 256 + koff, (char*)Bs + p * 4096 + tid * 16);
        }
        __syncthreads();

#pragma unroll
        for (int ks = 0; ks < 2; ++ks) {
            const int ra = wv * 16 + frow;
            const f16x8 af = *(const f16x8*)((char*)As + ra * 128 + (((ks * 4 + grp) ^ (ra & 7)) << 4));
#pragma unroll
            for (int j = 0; j < 8; ++j) {
                const int rb = j * 16 + frow;
                const f16x8 bf = *(const f16x8*)((char*)Bs + rb * 128 + (((ks * 4 + grp) ^ (rb & 7)) << 4));
                acc[j] = __builtin_amdgcn_mfma_f32_16x16x32_f16(af, bf, acc[j], 0, 0, 0);
            }
        }
    }

    if (g == 2) {
        // direct register epilogue: vt[(head*64+d)][n] fp16, 8B stores.
#pragma unroll
        for (int j = 0; j < 8; ++j) {
            const int dglob = c0 + j * 16 + frow;
            const int n = m0 + wv * 16 + grp * 4;
            f16x4 pv;
#pragma unroll
            for (int v = 0; v < 4; ++v) pv[v] = (_Float16)acc[j][v];
            *(f16x4*)&vt[((size_t)dglob << 12) + n] = pv;
        }
        return;
    }

    __syncthreads();
    _Float16* Epi = (_Float16*)psmem;            // [64][136] fp16 (17408 B)
    {
        const float scale = (g == 0) ? 0.125f : 1.f;
#pragma unroll
        for (int j = 0; j < 8; ++j) {
            const int rr = wv * 16 + grp * 4;
            const int cc = j * 16 + frow;
#pragma unroll
            for (int v = 0; v < 4; ++v) {
                float x = acc[j][v];
                x = (g == 3) ? 1.f / (1.f + __expf(-x)) : x * scale;
                Epi[(rr + v) * 136 + cc] = (_Float16)x;
            }
        }
    }
    __syncthreads();
    {
        const int ch   = tid & 15;
        const int head = ch >> 3;
        const int e8   = (ch & 7) * 8;
#pragma unroll
        for (int p = 0; p < 4; ++p) {
            const int r = p * 16 + (tid >> 4);
            const f16x8 val = *(const f16x8*)&Epi[r * 136 + head * 64 + e8];
            const int n = m0 + r;
            if (g == 3) {
                *(f16x8*)&gh[(size_t)n * HD_ + c0 + head * 64 + e8] = val;
            } else {
                _Float16* dst = (g == 0) ? qh : kh;
                const int hh = (c0 >> 6) + head;
                *(f16x8*)&dst[((size_t)hh * N_ + n) * D_ + e8] = val;
            }
        }
    }
}

// ---------------------------------------------------------------------------
// Kernel 2: local attention via fp16 MFMA. One block per (h,t), 4 waves.
// R21: T5 s_setprio(1) around the QK and PV MFMA clusters — with 4
// independent blocks/CU at different phases, the scheduler can favor the
// MFMA-issuing wave over sibling blocks' staging (m191 regime; the one
// untried catalog technique). Everything else R17.
// ---------------------------------------------------------------------------
__global__ __launch_bounds__(256, 4) void attn_mfma(
    const _Float16* __restrict__ qh, const _Float16* __restrict__ kh,
    const _Float16* __restrict__ vt, const float* __restrict__ bpF,
    const _Float16* __restrict__ gh, _Float16* __restrict__ of)
{
    __shared__ __align__(16) char smem[40960];
    _Float16* Qs = (_Float16*)smem;              // phase A: [64][64] swz, 8 KB
    char* Ks = smem + 8192;                      // phase A: [256][64] swz, 32 KB
    char* Ps = smem;                             // phase B: [64][128] swz, 16 KB
    char* Vs = smem + 16384;                     // phase B: [64 d][128 sl] swz, 16 KB
    float* Oe = (float*)smem;                    // epi: [64][68] fp32

    const int lb  = blockIdx.x;
    const int xcd = lb & 7;
    const int j_  = lb >> 3;
    const int h   = j_ >> 3;
    const int t   = xcd * 8 + (j_ & 7);
    const int tid = threadIdx.x;
    const int lane = tid & 63;
    const int wv = tid >> 6;
    const int frow = lane & 15;
    const int grp = lane >> 4;
    const int kbase = t * 64 - 96;

    const char* qbase = (const char*)qh + (size_t)(h * N_ + t * 64) * 128;
    const char* kbase_p = (const char*)kh + (size_t)h * N_ * 128;

#pragma unroll
    for (int q = 0; q < 2; ++q) {
        const int lin = q * 4096 + tid * 16;
        const int row = lin >> 7;
        const int ch = (lin >> 4) & 7;
        gload16(qbase + row * 128 + ((ch ^ (row & 7)) << 4), (char*)Qs + lin);
    }
#pragma unroll
    for (int q = 0; q < 8; ++q) {
        const int lin = q * 4096 + tid * 16;
        const int row = lin >> 7;              // 0..255
        const int ch = (lin >> 4) & 7;
        const int kg = kbase + row;
        if ((unsigned)kg < (unsigned)N_) {
            gload16(kbase_p + (size_t)kg * 128 + ((ch ^ (row & 7)) << 4), Ks + lin);
        } else {
            *(float4*)(Ks + lin) = make_float4(0.f, 0.f, 0.f, 0.f);
        }
    }

    // ---- bias -> accumulator init: 16 vector loads from packed band ----
    f32x4 sacc[16];
    {
        const float* bpT = bpF + (size_t)t * 16384;
        const int q0 = wv * 16 + grp * 4;
#pragma unroll
        for (int j = 0; j < 16; ++j)
            sacc[j] = *(const f32x4*)&bpT[(j * 16 + frow) * 64 + q0];
    }
    __syncthreads();   // Q+K staged

    {
        const int rq = wv * 16 + frow;
        __builtin_amdgcn_s_setprio(1);
#pragma unroll
        for (int ks = 0; ks < 2; ++ks) {
            const f16x8 aq = *(const f16x8*)((char*)Qs + rq * 128 + (((ks * 4 + grp) ^ (rq & 7)) << 4));
#pragma unroll
            for (int j = 0; j < 16; ++j) {
                const int rk = j * 16 + frow;     // slot 0..255
                const f16x8 bk = *(const f16x8*)(Ks + rk * 128 + (((ks * 4 + grp) ^ (rk & 7)) << 4));
                sacc[j] = __builtin_amdgcn_mfma_f32_16x16x32_f16(aq, bk, sacc[j], 0, 0, 0);
            }
        }
        __builtin_amdgcn_s_setprio(0);
    }
    __syncthreads();   // Q/K dead; phase B may overlay

    float inv[4];
    f32x4 oacc[4];
#pragma unroll
    for (int jd = 0; jd < 4; ++jd) oacc[jd] = (f32x4){0.f, 0.f, 0.f, 0.f};

#pragma unroll
    for (int c = 0; c < 2; ++c) {
        const int cb = kbase + c * 128;
        const bool bnd = (c == 0) ? (t <= 1) : (t >= 62);
        {
#pragma unroll
            for (int q = 0; q < 4; ++q) {
                const int lin = q * 4096 + tid * 16;
                const int d  = lin >> 8;                       // 0..63
                const int cs = (lin >> 4) & 15;                // stored 16B chunk
                const int cl = (cs & 8) | ((cs & 7) ^ (d & 7));// logical chunk
                const int kg0 = cb + cl * 8;
                const int kgc = kg0 < 0 ? 0 : (kg0 > N_ - 8 ? N_ - 8 : kg0);
                gload16(vt + (((size_t)(h * 64 + d)) << 12) + kgc, Vs + lin);
            }
        }
        if (c == 0) {
#pragma unroll
            for (int v = 0; v < 4; ++v) {
                float m = sacc[0][v];
#pragma unroll
                for (int f = 1; f < 16; ++f) m = fmaxf(m, sacc[f][v]);
                m = fmaxf(m, __shfl_xor(m, 1));
                m = fmaxf(m, __shfl_xor(m, 2));
                m = fmaxf(m, __shfl_xor(m, 4));
                m = fmaxf(m, __shfl_xor(m, 8));
                float l = 0.f;
#pragma unroll
                for (int f = 0; f < 16; ++f) {
                    float e = __expf(sacc[f][v] - m);
                    sacc[f][v] = e;
                    l += e;
                }
                l += __shfl_xor(l, 1);
                l += __shfl_xor(l, 2);
                l += __shfl_xor(l, 4);
                l += __shfl_xor(l, 8);
                inv[v] = 1.f / l;
            }
        }
        {
#pragma unroll
            for (int j = 0; j < 8; ++j) {
#pragma unroll
                for (int v = 0; v < 4; ++v) {
                    const int r = wv * 16 + grp * 4 + v;
                    const int byt = r * 256 + ((j * 32 + frow * 2) ^ ((r & 7) << 4));
                    *(_Float16*)(Ps + byt) = (_Float16)sacc[c * 8 + j][v];
                }
            }
        }
        __syncthreads();   // Ps writes + Vs gloads drained
        if (bnd) {
#pragma unroll
            for (int q = 0; q < 4; ++q) {
                const int lin = q * 4096 + tid * 16;
                const int d  = lin >> 8;
                const int cs = (lin >> 4) & 15;
                const int cl = (cs & 8) | ((cs & 7) ^ (d & 7));
                const int kg0 = cb + cl * 8;
                if ((unsigned)kg0 >= (unsigned)N_)
                    *(float4*)(Vs + lin) = make_float4(0.f, 0.f, 0.f, 0.f);
            }
            __syncthreads();
        }
        const int rp = wv * 16 + frow;
        __builtin_amdgcn_s_setprio(1);
#pragma unroll
        for (int ks = 0; ks < 4; ++ks) {
            const f16x8 ap = *(const f16x8*)(Ps + rp * 256 + (((ks * 4 + grp) ^ (rp & 7)) << 4));
#pragma unroll
            for (int jd = 0; jd < 4; ++jd) {
                const int rd = jd * 16 + frow;
                const f16x8 bv = *(const f16x8*)(Vs + rd * 256 + (((ks * 4 + grp) ^ (rd & 7)) << 4));
                oacc[jd] = __builtin_amdgcn_mfma_f32_16x16x32_f16(ap, bv, oacc[jd], 0, 0, 0);
            }
        }
        __builtin_amdgcn_s_setprio(0);
        __syncthreads();   // Ps/Vs reads done before restage / epi overlay
    }

#pragma unroll
    for (int jd = 0; jd < 4; ++jd) {
        const int dcol = jd * 16 + frow;
#pragma unroll
        for (int v = 0; v < 4; ++v) {
            const int rn = wv * 16 + grp * 4 + v;
            Oe[rn * 68 + dcol] = oacc[jd][v] * inv[v];
        }
    }
    __syncthreads();
    {
        const int r   = tid >> 2;
        const int seg = tid & 3;
        const int n   = t * 64 + r;
        const int cg0 = h * 64 + seg * 16;
        const float* orow = &Oe[r * 68 + seg * 16];
        f32x4 o0 = *(const f32x4*)&orow[0];
        f32x4 o1 = *(const f32x4*)&orow[4];
        f32x4 o2 = *(const f32x4*)&orow[8];
        f32x4 o3 = *(const f32x4*)&orow[12];
        const f16x8 g0 = *(const f16x8*)&gh[(size_t)n * HD_ + cg0];
        const f16x8 g1 = *(const f16x8*)&gh[(size_t)n * HD_ + cg0 + 8];
        f16x8 r0, r1;
#pragma unroll
        for (int e = 0; e < 4; ++e) {
            r0[e]     = (_Float16)(o0[e] * (float)g0[e]);
            r0[4 + e] = (_Float16)(o1[e] * (float)g0[4 + e]);
            r1[e]     = (_Float16)(o2[e] * (float)g1[e]);
            r1[4 + e] = (_Float16)(o3[e] * (float)g1[4 + e]);
        }
        *(f16x8*)&of[(size_t)n * HD_ + cg0]     = r0;
        *(f16x8*)&of[(size_t)n * HD_ + cg0 + 8] = r1;
    }
}

// ---------------------------------------------------------------------------
// Kernel 3: out = (o*g)[4096x1024] @ Wo[1024x256], fp16 MFMA. (R17,
// unchanged: 32x32 tiles, 1024 blocks = 4 blocks/CU, 2-phase dbuf prefetch.
// No setprio: lockstep GEMM blocks are the m190 null/negative regime.)
// ---------------------------------------------------------------------------
__global__ __launch_bounds__(256) void out_mfma(
    const _Float16* __restrict__ of, const _Float16* __restrict__ WoTf,
    float* __restrict__ out)
{
    __shared__ __align__(16) char smem[16384];   // 2 x {As 4KB, Bs 4KB}

    const int lb  = blockIdx.x;                  // 0..1023
    const int xcd = lb & 7;
    const int s   = lb >> 3;                     // 0..127
    const int rowt = (s >> 3) * 8 + xcd;         // 0..127
    const int m0  = rowt * 32;
    const int c0  = (s & 7) * 32;

    const int tid  = threadIdx.x;
    const int wave = tid >> 6;
    const int lane = tid & 63;
    const int wr   = wave >> 1;
    const int wc   = wave & 1;
    const int frow = lane & 15;
    const int grp  = lane >> 4;

    f32x4 acc = (f32x4){0.f, 0.f, 0.f, 0.f};

    auto STAGE = [&](char* bb, int kt) {
        const int row = tid >> 3;                // 0..31
        const int ch  = tid & 7;
        const int koff = kt + ((ch ^ (row & 7)) << 3);
        gload16(of + (size_t)(m0 + row) * HD_ + koff, bb + tid * 16);
        gload16(WoTf + (size_t)(c0 + row) * HD_ + koff, bb + 4096 + tid * 16);
    };

    STAGE(smem, 0);
    __syncthreads();                              // buf0 staged (drain)

    for (int t = 0; t < 16; ++t) {
        char* cur = smem + (t & 1) * 8192;
        if (t < 15) STAGE(smem + ((t + 1) & 1) * 8192, (t + 1) * 64);

        _Float16* As = (_Float16*)cur;
        _Float16* Bs = (_Float16*)(cur + 4096);
#pragma unroll
        for (int ks = 0; ks < 2; ++ks) {
            const int ra = wr * 16 + frow;
            const f16x8 af = *(const f16x8*)((char*)As + ra * 128 + (((ks * 4 + grp) ^ (ra & 7)) << 4));
            const int rb = wc * 16 + frow;
            const f16x8 bf = *(const f16x8*)((char*)Bs + rb * 128 + (((ks * 4 + grp) ^ (rb & 7)) << 4));
            acc = __builtin_amdgcn_mfma_f32_16x16x32_f16(af, bf, acc, 0, 0, 0);
        }
        __syncthreads();   // drains the prefetch (in flight during compute)
    }

    {
        const int c = c0 + wc * 16 + frow;
        const int rbase = grp * 4;
#pragma unroll
        for (int v = 0; v < 4; ++v) {
            const int n = m0 + wr * 16 + rbase + v;
            out[(size_t)n * C_ + c] = acc[v];
        }
    }
}

// ---------------------------------------------------------------------------
extern "C" void kernel_launch(void* const* d_in, const int* in_sizes, int n_in,
                              void* d_out, int out_size, void* d_ws, size_t ws_size,
                              hipStream_t stream)
{
    const float* q_x  = (const float*)d_in[0];
    const float* kv_x = (const float*)d_in[1];
    const float* bias = (const float*)d_in[2];
    const float* Wq   = (const float*)d_in[3];
    const float* Wk   = (const float*)d_in[4];
    const float* Wv   = (const float*)d_in[5];
    const float* Wg   = (const float*)d_in[6];
    const float* Wo   = (const float*)d_in[7];
    float* out = (float*)d_out;

    char* ws = (char*)d_ws;
    const size_t MB = 1048576;
    _Float16* qh   = (_Float16*)(ws);             // [16][4096][64] fp16, pre-scaled 1/8
    _Float16* kh   = (_Float16*)(ws + 8  * MB);
    _Float16* vt   = (_Float16*)(ws + 16 * MB);   // [1024 hd][4096 n] fp16 (transposed V)
    _Float16* gh   = (_Float16*)(ws + 24 * MB);   // [4096][1024] fp16 sigmoid gate
    _Float16* of   = (_Float16*)(ws + 32 * MB);   // [4096][1024] fp16 gated attn out
    _Float16* Xf   = (_Float16*)(ws + 40 * MB);   // [2][4096][256] fp16
    _Float16* WTf  = (_Float16*)(ws + 44 * MB);   // [4][1024][256] fp16
    _Float16* WoTf = (_Float16*)(ws + 46 * MB);   // [256][1024] fp16
    float*    bpF  = (float*)   (ws + 48 * MB);   // [64 t][256 s][64 q] fp32 bias band

    convert_kernel<<<896, 256, 0, stream>>>(q_x, kv_x, bias, Wq, Wk, Wv, Wg, Wo,
                                            Xf, WTf, WoTf, bpF);
    proj_mfma<<<2048, 256, 0, stream>>>(Xf, WTf, qh, kh, vt, gh);
    attn_mfma<<<1024, 256, 0, stream>>>(qh, kh, vt, bpF, gh, of);
    out_mfma<<<1024, 256, 0, stream>>>(of, WoTf, out);
}

// Round 15
// 159.470 us; speedup vs baseline: 1.0370x; 1.0370x over previous
//
#include <hip/hip_runtime.h>

#define N_ 4096
#define C_ 256
#define H_ 16
#define D_ 64
#define HD_ 1024

typedef __attribute__((ext_vector_type(8))) _Float16 f16x8;
typedef __attribute__((ext_vector_type(4))) _Float16 f16x4;
typedef __attribute__((ext_vector_type(4))) float f32x4;

__device__ __forceinline__ void gload16(const void* g, void* l) {
    __builtin_amdgcn_global_load_lds(
        (const __attribute__((address_space(1))) unsigned int*)g,
        (__attribute__((address_space(3))) unsigned int*)l, 16, 0, 0);
}

// ---------------------------------------------------------------------------
// Kernel 0: convert fp32 inputs -> fp16 (X, Wq..Wg, Wo). W transposed
// K-contiguous. (R16 exact — the best harness-verified config, 160.7 us.)
// ---------------------------------------------------------------------------
__global__ __launch_bounds__(256) void convert_kernel(
    const float* __restrict__ q_x, const float* __restrict__ kv_x,
    const float* __restrict__ Wq, const float* __restrict__ Wk,
    const float* __restrict__ Wv, const float* __restrict__ Wg,
    const float* __restrict__ Wo,
    _Float16* __restrict__ Xf, _Float16* __restrict__ WTf,
    _Float16* __restrict__ WoTf)
{
    __shared__ float ts[64][65];
    const int b = blockIdx.x;
    const int tid = threadIdx.x;

    if (b < 512) {
        const int seg = b >> 8;
        const float* src = seg ? kv_x : q_x;
        _Float16* df = Xf + (size_t)seg * 1048576;
        const int base = (b & 255) * 4096 + tid * 16;
#pragma unroll
        for (int q = 0; q < 4; ++q) {
            float4 v = *(const float4*)&src[base + q * 4];
            f16x4 fv;
            fv[0] = (_Float16)v.x; fv[1] = (_Float16)v.y;
            fv[2] = (_Float16)v.z; fv[3] = (_Float16)v.w;
            *(f16x4*)&df[base + q * 4] = fv;
        }
        return;
    }

    const float* src;
    _Float16* df;
    int srcC, dstC, r0, c0;
    if (b < 768) {
        const int widx = (b - 512) >> 6;
        const int tile = (b - 512) & 63;
        src = (widx == 0) ? Wq : (widx == 1) ? Wk : (widx == 2) ? Wv : Wg;
        df = WTf + (size_t)widx * 262144;
        srcC = 1024; dstC = 256;
        r0 = (tile >> 4) * 64;
        c0 = (tile & 15) * 64;
    } else {
        const int tile = b - 768;
        src = Wo; df = WoTf;
        srcC = 256; dstC = 1024;
        r0 = (tile >> 2) * 64;
        c0 = (tile & 3) * 64;
    }
    {
        const int r = tid >> 2;
        const int cch = (tid & 3) * 16;
#pragma unroll
        for (int q = 0; q < 4; ++q) {
            float4 v = *(const float4*)&src[(size_t)(r0 + r) * srcC + c0 + cch + q * 4];
            ts[r][cch + q * 4 + 0] = v.x;
            ts[r][cch + q * 4 + 1] = v.y;
            ts[r][cch + q * 4 + 2] = v.z;
            ts[r][cch + q * 4 + 3] = v.w;
        }
    }
    __syncthreads();
    {
        const int c = tid >> 2;
        const int rch = (tid & 3) * 16;
#pragma unroll
        for (int q = 0; q < 4; ++q) {
            f16x4 fv;
#pragma unroll
            for (int j = 0; j < 4; ++j)
                fv[j] = (_Float16)ts[rch + q * 4 + j][c];
            *(f16x4*)&df[(size_t)(c0 + c) * dstC + r0 + rch + q * 4] = fv;
        }
    }
}

// ---------------------------------------------------------------------------
// Kernel 1: projections via fp16 MFMA. 64x128 tile -> 2048 blocks, LDS
// 24 KB -> 6 blocks/CU (TLP is the binding resource in this latency-bound
// regime: R14 2/CU regressed 66%, R18 counted-vmcnt at 3/CU −5us, R20
// 64x64 neutral). BK=64, XOR-8 swizzle, XCD clustering. g==2 (V) direct
// register epilogue to transposed vt.
// ---------------------------------------------------------------------------
__global__ __launch_bounds__(256) void proj_mfma(
    const _Float16* __restrict__ Xf, const _Float16* __restrict__ WTf,
    _Float16* __restrict__ qh, _Float16* __restrict__ kh,
    _Float16* __restrict__ vt, _Float16* __restrict__ gh)
{
    __shared__ __align__(16) char psmem[24576];
    _Float16* As = (_Float16*)psmem;             // [64][64] swz, 8 KB
    _Float16* Bs = (_Float16*)(psmem + 8192);    // [128][64] swz, 16 KB

    const int lb  = blockIdx.x;                  // 0..2047
    const int xcd = lb & 7;
    const int gr  = (lb >> 6) * 8 + xcd;         // 0..255 -> (g, row-tile)
    const int g   = gr >> 6;
    const int m0  = (gr & 63) * 64;
    const int c0  = ((lb >> 3) & 7) * 128;

    const _Float16* A = Xf + ((g == 1 || g == 2) ? 1048576 : 0);
    const _Float16* B = WTf + (size_t)g * 262144;

    const int tid  = threadIdx.x;
    const int wv   = tid >> 6;                   // wave 0..3 = 16-row strip
    const int lane = tid & 63;
    const int frow = lane & 15;
    const int grp  = lane >> 4;

    f32x4 acc[8];
#pragma unroll
    for (int j = 0; j < 8; ++j) acc[j] = (f32x4){0.f, 0.f, 0.f, 0.f};

    const int srow = tid >> 3;
    const int sch  = tid & 7;

    for (int kt = 0; kt < 256; kt += 64) {
        __syncthreads();
#pragma unroll
        for (int p = 0; p < 2; ++p) {            // A: 64 rows x 64 k = 8 KB
            const int row = p * 32 + srow;
            const int koff = kt + ((sch ^ (row & 7)) << 3);
            gload16(A + (size_t)(m0 + row) * 256 + koff, (char*)As + p * 4096 + tid * 16);
        }
#pragma unroll
        for (int p = 0; p < 4; ++p) {            // B: 128 rows x 64 k = 16 KB
            const int row = p * 32 + srow;
            const int koff = kt + ((sch ^ (row & 7)) << 3);
            gload16(B + (size_t)(c0 + row) * 256 + koff, (char*)Bs + p * 4096 + tid * 16);
        }
        __syncthreads();

#pragma unroll
        for (int ks = 0; ks < 2; ++ks) {
            const int ra = wv * 16 + frow;
            const f16x8 af = *(const f16x8*)((char*)As + ra * 128 + (((ks * 4 + grp) ^ (ra & 7)) << 4));
#pragma unroll
            for (int j = 0; j < 8; ++j) {
                const int rb = j * 16 + frow;
                const f16x8 bf = *(const f16x8*)((char*)Bs + rb * 128 + (((ks * 4 + grp) ^ (rb & 7)) << 4));
                acc[j] = __builtin_amdgcn_mfma_f32_16x16x32_f16(af, bf, acc[j], 0, 0, 0);
            }
        }
    }

    if (g == 2) {
        // direct register epilogue: vt[(head*64+d)][n] fp16, 8B stores.
#pragma unroll
        for (int j = 0; j < 8; ++j) {
            const int dglob = c0 + j * 16 + frow;
            const int n = m0 + wv * 16 + grp * 4;
            f16x4 pv;
#pragma unroll
            for (int v = 0; v < 4; ++v) pv[v] = (_Float16)acc[j][v];
            *(f16x4*)&vt[((size_t)dglob << 12) + n] = pv;
        }
        return;
    }

    __syncthreads();
    _Float16* Epi = (_Float16*)psmem;            // [64][136] fp16 (17408 B)
    {
        const float scale = (g == 0) ? 0.125f : 1.f;
#pragma unroll
        for (int j = 0; j < 8; ++j) {
            const int rr = wv * 16 + grp * 4;
            const int cc = j * 16 + frow;
#pragma unroll
            for (int v = 0; v < 4; ++v) {
                float x = acc[j][v];
                x = (g == 3) ? 1.f / (1.f + __expf(-x)) : x * scale;
                Epi[(rr + v) * 136 + cc] = (_Float16)x;
            }
        }
    }
    __syncthreads();
    {
        const int ch   = tid & 15;
        const int head = ch >> 3;
        const int e8   = (ch & 7) * 8;
#pragma unroll
        for (int p = 0; p < 4; ++p) {
            const int r = p * 16 + (tid >> 4);
            const f16x8 val = *(const f16x8*)&Epi[r * 136 + head * 64 + e8];
            const int n = m0 + r;
            if (g == 3) {
                *(f16x8*)&gh[(size_t)n * HD_ + c0 + head * 64 + e8] = val;
            } else {
                _Float16* dst = (g == 0) ? qh : kh;
                const int hh = (c0 >> 6) + head;
                *(f16x8*)&dst[((size_t)hh * N_ + n) * D_ + e8] = val;
            }
        }
    }
}

// ---------------------------------------------------------------------------
// Kernel 2: local attention via fp16 MFMA. One block per (h,t), 4 waves.
// (R13/R16 verified: gload16's LDS dest is wave-uniform base + lane*16;
// V staging always issues full-exec with clamped global address, boundary
// trunks zero OOB chunks behind a barrier. Scalar bias init, hides under
// async Q/K staging.)
// ---------------------------------------------------------------------------
__global__ __launch_bounds__(256, 4) void attn_mfma(
    const _Float16* __restrict__ qh, const _Float16* __restrict__ kh,
    const _Float16* __restrict__ vt, const float* __restrict__ bias,
    const _Float16* __restrict__ gh, _Float16* __restrict__ of)
{
    __shared__ __align__(16) char smem[40960];
    _Float16* Qs = (_Float16*)smem;              // phase A: [64][64] swz, 8 KB
    char* Ks = smem + 8192;                      // phase A: [256][64] swz, 32 KB
    char* Ps = smem;                             // phase B: [64][128] swz, 16 KB
    char* Vs = smem + 16384;                     // phase B: [64 d][128 sl] swz, 16 KB
    float* Oe = (float*)smem;                    // epi: [64][68] fp32

    const int lb  = blockIdx.x;
    const int xcd = lb & 7;
    const int j_  = lb >> 3;
    const int h   = j_ >> 3;
    const int t   = xcd * 8 + (j_ & 7);
    const int tid = threadIdx.x;
    const int lane = tid & 63;
    const int wv = tid >> 6;
    const int frow = lane & 15;
    const int grp = lane >> 4;
    const int kbase = t * 64 - 96;

    const char* qbase = (const char*)qh + (size_t)(h * N_ + t * 64) * 128;
    const char* kbase_p = (const char*)kh + (size_t)h * N_ * 128;

#pragma unroll
    for (int q = 0; q < 2; ++q) {
        const int lin = q * 4096 + tid * 16;
        const int row = lin >> 7;
        const int ch = (lin >> 4) & 7;
        gload16(qbase + row * 128 + ((ch ^ (row & 7)) << 4), (char*)Qs + lin);
    }
#pragma unroll
    for (int q = 0; q < 8; ++q) {
        const int lin = q * 4096 + tid * 16;
        const int row = lin >> 7;              // 0..255
        const int ch = (lin >> 4) & 7;
        const int kg = kbase + row;
        if ((unsigned)kg < (unsigned)N_) {
            gload16(kbase_p + (size_t)kg * 128 + ((ch ^ (row & 7)) << 4), Ks + lin);
        } else {
            *(float4*)(Ks + lin) = make_float4(0.f, 0.f, 0.f, 0.f);
        }
    }

    f32x4 sacc[16];
    {
        const int rowg = t * 64 + wv * 16 + grp * 4;
#pragma unroll
        for (int j = 0; j < 16; ++j) {
            const int colg = kbase + j * 16 + frow;
            const bool ok = (unsigned)colg < (unsigned)N_;
#pragma unroll
            for (int v = 0; v < 4; ++v)
                sacc[j][v] = ok ? bias[(size_t)(rowg + v) * N_ + colg] : 0.f;
        }
    }
    __syncthreads();   // Q+K staged

    {
        const int rq = wv * 16 + frow;
#pragma unroll
        for (int ks = 0; ks < 2; ++ks) {
            const f16x8 aq = *(const f16x8*)((char*)Qs + rq * 128 + (((ks * 4 + grp) ^ (rq & 7)) << 4));
#pragma unroll
            for (int j = 0; j < 16; ++j) {
                const int rk = j * 16 + frow;     // slot 0..255
                const f16x8 bk = *(const f16x8*)(Ks + rk * 128 + (((ks * 4 + grp) ^ (rk & 7)) << 4));
                sacc[j] = __builtin_amdgcn_mfma_f32_16x16x32_f16(aq, bk, sacc[j], 0, 0, 0);
            }
        }
    }
    __syncthreads();   // Q/K dead; phase B may overlay

    float inv[4];
    f32x4 oacc[4];
#pragma unroll
    for (int jd = 0; jd < 4; ++jd) oacc[jd] = (f32x4){0.f, 0.f, 0.f, 0.f};

#pragma unroll
    for (int c = 0; c < 2; ++c) {
        const int cb = kbase + c * 128;
        const bool bnd = (c == 0) ? (t <= 1) : (t >= 62);
        {
#pragma unroll
            for (int q = 0; q < 4; ++q) {
                const int lin = q * 4096 + tid * 16;
                const int d  = lin >> 8;                       // 0..63
                const int cs = (lin >> 4) & 15;                // stored 16B chunk
                const int cl = (cs & 8) | ((cs & 7) ^ (d & 7));// logical chunk
                const int kg0 = cb + cl * 8;
                const int kgc = kg0 < 0 ? 0 : (kg0 > N_ - 8 ? N_ - 8 : kg0);
                gload16(vt + (((size_t)(h * 64 + d)) << 12) + kgc, Vs + lin);
            }
        }
        if (c == 0) {
#pragma unroll
            for (int v = 0; v < 4; ++v) {
                float m = sacc[0][v];
#pragma unroll
                for (int f = 1; f < 16; ++f) m = fmaxf(m, sacc[f][v]);
                m = fmaxf(m, __shfl_xor(m, 1));
                m = fmaxf(m, __shfl_xor(m, 2));
                m = fmaxf(m, __shfl_xor(m, 4));
                m = fmaxf(m, __shfl_xor(m, 8));
                float l = 0.f;
#pragma unroll
                for (int f = 0; f < 16; ++f) {
                    float e = __expf(sacc[f][v] - m);
                    sacc[f][v] = e;
                    l += e;
                }
                l += __shfl_xor(l, 1);
                l += __shfl_xor(l, 2);
                l += __shfl_xor(l, 4);
                l += __shfl_xor(l, 8);
                inv[v] = 1.f / l;
            }
        }
        {
#pragma unroll
            for (int j = 0; j < 8; ++j) {
#pragma unroll
                for (int v = 0; v < 4; ++v) {
                    const int r = wv * 16 + grp * 4 + v;
                    const int byt = r * 256 + ((j * 32 + frow * 2) ^ ((r & 7) << 4));
                    *(_Float16*)(Ps + byt) = (_Float16)sacc[c * 8 + j][v];
                }
            }
        }
        __syncthreads();   // Ps writes + Vs gloads drained
        if (bnd) {
#pragma unroll
            for (int q = 0; q < 4; ++q) {
                const int lin = q * 4096 + tid * 16;
                const int d  = lin >> 8;
                const int cs = (lin >> 4) & 15;
                const int cl = (cs & 8) | ((cs & 7) ^ (d & 7));
                const int kg0 = cb + cl * 8;
                if ((unsigned)kg0 >= (unsigned)N_)
                    *(float4*)(Vs + lin) = make_float4(0.f, 0.f, 0.f, 0.f);
            }
            __syncthreads();
        }
        const int rp = wv * 16 + frow;
#pragma unroll
        for (int ks = 0; ks < 4; ++ks) {
            const f16x8 ap = *(const f16x8*)(Ps + rp * 256 + (((ks * 4 + grp) ^ (rp & 7)) << 4));
#pragma unroll
            for (int jd = 0; jd < 4; ++jd) {
                const int rd = jd * 16 + frow;
                const f16x8 bv = *(const f16x8*)(Vs + rd * 256 + (((ks * 4 + grp) ^ (rd & 7)) << 4));
                oacc[jd] = __builtin_amdgcn_mfma_f32_16x16x32_f16(ap, bv, oacc[jd], 0, 0, 0);
            }
        }
        __syncthreads();   // Ps/Vs reads done before restage / epi overlay
    }

#pragma unroll
    for (int jd = 0; jd < 4; ++jd) {
        const int dcol = jd * 16 + frow;
#pragma unroll
        for (int v = 0; v < 4; ++v) {
            const int rn = wv * 16 + grp * 4 + v;
            Oe[rn * 68 + dcol] = oacc[jd][v] * inv[v];
        }
    }
    __syncthreads();
    {
        const int r   = tid >> 2;
        const int seg = tid & 3;
        const int n   = t * 64 + r;
        const int cg0 = h * 64 + seg * 16;
        const float* orow = &Oe[r * 68 + seg * 16];
        f32x4 o0 = *(const f32x4*)&orow[0];
        f32x4 o1 = *(const f32x4*)&orow[4];
        f32x4 o2 = *(const f32x4*)&orow[8];
        f32x4 o3 = *(const f32x4*)&orow[12];
        const f16x8 g0 = *(const f16x8*)&gh[(size_t)n * HD_ + cg0];
        const f16x8 g1 = *(const f16x8*)&gh[(size_t)n * HD_ + cg0 + 8];
        f16x8 r0, r1;
#pragma unroll
        for (int e = 0; e < 4; ++e) {
            r0[e]     = (_Float16)(o0[e] * (float)g0[e]);
            r0[4 + e] = (_Float16)(o1[e] * (float)g0[4 + e]);
            r1[e]     = (_Float16)(o2[e] * (float)g1[e]);
            r1[4 + e] = (_Float16)(o3[e] * (float)g1[4 + e]);
        }
        *(f16x8*)&of[(size_t)n * HD_ + cg0]     = r0;
        *(f16x8*)&of[(size_t)n * HD_ + cg0 + 8] = r1;
    }
}

// ---------------------------------------------------------------------------
// Kernel 3: out = (o*g)[4096x1024] @ Wo[1024x256], fp16 MFMA. 2-phase
// double-buffered prefetch, 32x64 tiles, 512 blocks. (R15/R16 verified)
// ---------------------------------------------------------------------------
__global__ __launch_bounds__(256) void out_mfma(
    const _Float16* __restrict__ of, const _Float16* __restrict__ WoTf,
    float* __restrict__ out)
{
    __shared__ __align__(16) char smem[24576];   // 2 x {As 4KB, Bs 8KB}

    const int lb  = blockIdx.x;
    const int xcd = lb & 7;
    const int s   = lb >> 3;                 // 0..63
    const int rowt = (s >> 2) * 8 + xcd;     // 0..127
    const int m0  = rowt * 32;
    const int c0  = (s & 3) * 64;

    const int tid  = threadIdx.x;
    const int wave = tid >> 6;
    const int lane = tid & 63;
    const int wr   = wave >> 1;
    const int wc   = wave & 1;
    const int frow = lane & 15;
    const int grp  = lane >> 4;

    f32x4 acc[2];
#pragma unroll
    for (int j = 0; j < 2; ++j) acc[j] = (f32x4){0.f, 0.f, 0.f, 0.f};

    auto STAGE = [&](char* bb, int kt) {
        {
            const int row = tid >> 3;            // 0..31
            const int ch  = tid & 7;
            const int koff = kt + ((ch ^ (row & 7)) << 3);
            gload16(of + (size_t)(m0 + row) * HD_ + koff, bb + tid * 16);
        }
#pragma unroll
        for (int p = 0; p < 2; ++p) {
            const int lin = p * 4096 + tid * 16;
            const int row = lin >> 7;            // 0..63
            const int ch  = (lin >> 4) & 7;
            const int koff = kt + ((ch ^ (row & 7)) << 3);
            gload16(WoTf + (size_t)(c0 + row) * HD_ + koff, bb + 4096 + lin);
        }
    };

    STAGE(smem, 0);
    __syncthreads();                              // buf0 staged (drain)

    for (int t = 0; t < 16; ++t) {
        char* cur = smem + (t & 1) * 12288;
        if (t < 15) STAGE(smem + ((t + 1) & 1) * 12288, (t + 1) * 64);

        _Float16* As = (_Float16*)cur;
        _Float16* Bs = (_Float16*)(cur + 4096);
#pragma unroll
        for (int ks = 0; ks < 2; ++ks) {
            const int ra = wr * 16 + frow;
            const f16x8 af = *(const f16x8*)((char*)As + ra * 128 + (((ks * 4 + grp) ^ (ra & 7)) << 4));
#pragma unroll
            for (int j = 0; j < 2; ++j) {
                const int rb = wc * 32 + j * 16 + frow;
                const f16x8 bf = *(const f16x8*)((char*)Bs + rb * 128 + (((ks * 4 + grp) ^ (rb & 7)) << 4));
                acc[j] = __builtin_amdgcn_mfma_f32_16x16x32_f16(af, bf, acc[j], 0, 0, 0);
            }
        }
        __syncthreads();   // drains the prefetch (in flight during compute)
    }

    const int rbase = grp * 4;
#pragma unroll
    for (int j = 0; j < 2; ++j) {
        const int c = c0 + wc * 32 + j * 16 + frow;
#pragma unroll
        for (int v = 0; v < 4; ++v) {
            const int n = m0 + wr * 16 + rbase + v;
            out[(size_t)n * C_ + c] = acc[j][v];
        }
    }
}

// ---------------------------------------------------------------------------
extern "C" void kernel_launch(void* const* d_in, const int* in_sizes, int n_in,
                              void* d_out, int out_size, void* d_ws, size_t ws_size,
                              hipStream_t stream)
{
    const float* q_x  = (const float*)d_in[0];
    const float* kv_x = (const float*)d_in[1];
    const float* bias = (const float*)d_in[2];
    const float* Wq   = (const float*)d_in[3];
    const float* Wk   = (const float*)d_in[4];
    const float* Wv   = (const float*)d_in[5];
    const float* Wg   = (const float*)d_in[6];
    const float* Wo   = (const float*)d_in[7];
    float* out = (float*)d_out;

    char* ws = (char*)d_ws;
    const size_t MB = 1048576;
    _Float16* qh   = (_Float16*)(ws);             // [16][4096][64] fp16, pre-scaled 1/8
    _Float16* kh   = (_Float16*)(ws + 8  * MB);
    _Float16* vt   = (_Float16*)(ws + 16 * MB);   // [1024 hd][4096 n] fp16 (transposed V)
    _Float16* gh   = (_Float16*)(ws + 24 * MB);   // [4096][1024] fp16 sigmoid gate
    _Float16* of   = (_Float16*)(ws + 32 * MB);   // [4096][1024] fp16 gated attn out
    _Float16* Xf   = (_Float16*)(ws + 40 * MB);   // [2][4096][256] fp16
    _Float16* WTf  = (_Float16*)(ws + 44 * MB);   // [4][1024][256] fp16
    _Float16* WoTf = (_Float16*)(ws + 46 * MB);   // [256][1024] fp16

    convert_kernel<<<832, 256, 0, stream>>>(q_x, kv_x, Wq, Wk, Wv, Wg, Wo,
                                            Xf, WTf, WoTf);
    proj_mfma<<<2048, 256, 0, stream>>>(Xf, WTf, qh, kh, vt, gh);
    attn_mfma<<<1024, 256, 0, stream>>>(qh, kh, vt, bias, gh, of);
    out_mfma<<<512, 256, 0, stream>>>(of, WoTf, out);
}